// Round 20
// baseline (179.880 us; speedup 1.0000x reference)
//
#include <hip/hip_runtime.h>
#include <math.h>

// ---------------------------------------------------------------------------
// Bidirectional Mamba block, MI355X. Round 20 (= round 19 resubmit; infra fail):
//  - out_proj back to DIRECT K=2048 GEMM -> out (r17's split-K measured
//    neutral; with p3c fusion it's pure overhead: 33.5MB partials + 1 launch).
//    oreduce deleted. 10 launches.
//  - all else byte-identical to r18 (verified, 173.4us).
// ws layout (f32 elements):
//   xz    region: xz16 fp16 (dead after p3c)
//   u     region: [0,2.1M) H16+Win16 -> hinit16 | [3M,7M) u16 | [7M,8M) Wout16
//   xdbl  [dirb][96][1024] f32
//   delta region: [0,4.2M) delta16 | [4.2M,7.3M) xpb partials
//   y     region: scratch -> hend16|aprod16 (dead after carry) -> GT [0,2.1M)
// ---------------------------------------------------------------------------

typedef _Float16 f16x8 __attribute__((ext_vector_type(8)));
typedef _Float16 f16x4 __attribute__((ext_vector_type(4)));
typedef float    f32x4 __attribute__((ext_vector_type(4)));

#define SCH 32    // scan chunks
#define SCL 32    // chunk length

__device__ __forceinline__ void gload_lds16(const void* g, void* l) {
    __builtin_amdgcn_global_load_lds(
        (const __attribute__((address_space(1))) void*)g,
        (__attribute__((address_space(3))) void*)l, 16, 0, 0);
}

__device__ __forceinline__ float softplus_f(float x) {
    float e = __builtin_amdgcn_exp2f(-fabsf(x) * 1.44269504f);
    return fmaxf(x, 0.f) + __builtin_amdgcn_logf(1.f + e) * 0.69314718f;
}

template<int CTRL>
__device__ __forceinline__ float dpp_add(float x) {
    int s = __builtin_amdgcn_update_dpp(0, __builtin_bit_cast(int, x),
                                        CTRL, 0xF, 0xF, true);
    return x + __builtin_bit_cast(float, s);
}

// ---------------------------------------------------------------------------
// fp16 NT MFMA GEMM (verified r17). z-dim: A += z*sA, B += z*sB, C += z*sC.
// ---------------------------------------------------------------------------
template<int WMW, int WNW, int FM, int FN, typename CT>
__global__ __launch_bounds__(256)
void gemm_nt_f16(const _Float16* __restrict__ A, const _Float16* __restrict__ B,
                 CT* __restrict__ C, int K, int lda, int ldc,
                 long sA, long sB, long sC)
{
    constexpr int BM = WMW * FM * 16, BN = WNW * FN * 16;
    constexpr int ACH = BM / 8, NCH = (BM + BN) / 8;
    __shared__ __align__(16) _Float16 lds[(BM + BN) * 64];
    A += (long)blockIdx.z * sA;
    B += (long)blockIdx.z * sB;
    C += (long)blockIdx.z * sC;
    const int m0 = blockIdx.y * BM, n0 = blockIdx.x * BN;
    const int t = threadIdx.x, wid = t >> 6, lane = t & 63;
    const int wm = wid / WNW, wn = wid % WNW;
    const int srow = lane >> 3;
    const int skk  = ((lane & 7) ^ srow) * 8;

    f32x4 acc[FM][FN];
#pragma unroll
    for (int i = 0; i < FM; ++i)
#pragma unroll
        for (int j = 0; j < FN; ++j) acc[i][j] = (f32x4){0.f, 0.f, 0.f, 0.f};

    for (int k0 = 0; k0 < K; k0 += 64) {
#pragma unroll
        for (int c = wid; c < NCH; c += 4) {
            const _Float16* gp = (c < ACH)
                ? A + (long)(m0 + c * 8 + srow) * lda + k0 + skk
                : B + (long)(n0 + (c - ACH) * 8 + srow) * lda + k0 + skk;
            gload_lds16(gp, lds + c * 512);
        }
        __syncthreads();
#pragma unroll
        for (int kw = 0; kw < 2; ++kw) {
            f16x8 af[FM], bf[FN];
#pragma unroll
            for (int i = 0; i < FM; ++i) {
                int r = wm * FM * 16 + i * 16 + (lane & 15);
                af[i] = *(const f16x8*)(lds + r * 64 +
                        (((kw * 4 + (lane >> 4)) ^ (r & 7)) * 8));
            }
#pragma unroll
            for (int j = 0; j < FN; ++j) {
                int r = wn * FN * 16 + j * 16 + (lane & 15);
                bf[j] = *(const f16x8*)(lds + BM * 64 + r * 64 +
                        (((kw * 4 + (lane >> 4)) ^ (r & 7)) * 8));
            }
#pragma unroll
            for (int i = 0; i < FM; ++i)
#pragma unroll
                for (int j = 0; j < FN; ++j)
                    acc[i][j] = __builtin_amdgcn_mfma_f32_16x16x32_f16(
                        af[i], bf[j], acc[i][j], 0, 0, 0);
        }
        __syncthreads();
    }
#pragma unroll
    for (int i = 0; i < FM; ++i)
#pragma unroll
        for (int j = 0; j < FN; ++j) {
            int n = n0 + wn * FN * 16 + j * 16 + (lane & 15);
            int m = m0 + wm * FM * 16 + i * 16 + (lane >> 4) * 4;
            f32x4 v = acc[i][j];
            if constexpr (__is_same(CT, float)) {
                *(f32x4*)&C[(long)n * ldc + m] = v;
            } else {
                f16x4 h = {(_Float16)v.x, (_Float16)v.y, (_Float16)v.z, (_Float16)v.w};
                *(f16x4*)&C[(long)n * ldc + m] = h;
            }
        }
}

// ---------------------------------------------------------------------------
// x_proj fp16 MFMA, split-K (verified r8/r14).
// ---------------------------------------------------------------------------
#define XP_SK 8
__global__ __launch_bounds__(256)
void xproj_f16_kernel(const _Float16* __restrict__ u16, const _Float16* __restrict__ xw16,
                      float* __restrict__ pb)
{
    __shared__ __align__(16) _Float16 Asw[128 * 64];
    __shared__ __align__(16) _Float16 Bsw[96 * 64];
    const int t = threadIdx.x, wid = t >> 6, lane = t & 63;
    const int wm = wid >> 1, wn = wid & 1;
    const int m0 = blockIdx.x * 128;
    const int sk = blockIdx.y, dirb = blockIdx.z;
    const _Float16* ub = u16 + (long)dirb * 2048 * 1024;
    const _Float16* Bw = xw16 + (long)(dirb >> 1) * 96 * 2048;
    const int srow = lane >> 3;
    const int skk  = ((lane & 7) ^ srow) * 8;
    const int lloc = (t & 31) * 4;
    const int kslt = t >> 5;

    f32x4 acc[4][3];
#pragma unroll
    for (int i = 0; i < 4; ++i)
#pragma unroll
        for (int j = 0; j < 3; ++j) acc[i][j] = (f32x4){0.f, 0.f, 0.f, 0.f};

    for (int ks = 0; ks < 2048 / XP_SK; ks += 64) {
        const int k0 = sk * (2048 / XP_SK) + ks;
#pragma unroll
        for (int c = wid; c < 12; c += 4)
            gload_lds16(Bw + (long)(c * 8 + srow) * 2048 + k0 + skk, Bsw + c * 512);
        _Float16 av[8][4];
#pragma unroll
        for (int kk = 0; kk < 8; ++kk) {
            f16x4 v = *(const f16x4*)&ub[(long)(k0 + kslt * 8 + kk) * 1024 + m0 + lloc];
            av[kk][0] = v[0]; av[kk][1] = v[1]; av[kk][2] = v[2]; av[kk][3] = v[3];
        }
#pragma unroll
        for (int q = 0; q < 4; ++q) {
            int l = lloc + q;
            f16x8 h = {av[0][q], av[1][q], av[2][q], av[3][q],
                       av[4][q], av[5][q], av[6][q], av[7][q]};
            *(f16x8*)(Asw + l * 64 + ((kslt ^ (l & 7)) * 8)) = h;
        }
        __syncthreads();
#pragma unroll
        for (int kw = 0; kw < 2; ++kw) {
            f16x8 af[4], bf[3];
#pragma unroll
            for (int i = 0; i < 4; ++i) {
                int r = wm * 64 + i * 16 + (lane & 15);
                af[i] = *(const f16x8*)(Asw + r * 64 +
                        (((kw * 4 + (lane >> 4)) ^ (r & 7)) * 8));
            }
#pragma unroll
            for (int j = 0; j < 3; ++j) {
                int r = wn * 48 + j * 16 + (lane & 15);
                bf[j] = *(const f16x8*)(Bsw + r * 64 +
                        (((kw * 4 + (lane >> 4)) ^ (r & 7)) * 8));
            }
#pragma unroll
            for (int i = 0; i < 4; ++i)
#pragma unroll
                for (int j = 0; j < 3; ++j)
                    acc[i][j] = __builtin_amdgcn_mfma_f32_16x16x32_f16(
                        af[i], bf[j], acc[i][j], 0, 0, 0);
        }
        __syncthreads();
    }
    float* Cp = pb + ((long)sk * 4 + dirb) * 96 * 1024;
#pragma unroll
    for (int i = 0; i < 4; ++i)
#pragma unroll
        for (int j = 0; j < 3; ++j) {
            int n = wn * 48 + j * 16 + (lane & 15);
            int m = m0 + wm * 64 + i * 16 + (lane >> 4) * 4;
            *(f32x4*)&Cp[(long)n * 1024 + m] = acc[i][j];
        }
}

__global__ __launch_bounds__(256)
void xreduce_kernel(const float* __restrict__ pb, float* __restrict__ xdbl)
{
    int f = (blockIdx.x * 256 + threadIdx.x) * 4;
    f32x4 s = (f32x4){0.f, 0.f, 0.f, 0.f};
#pragma unroll
    for (int sk = 0; sk < XP_SK; ++sk)
        s += *(const f32x4*)(pb + (long)sk * 393216 + f);
    *(f32x4*)(xdbl + f) = s;
}

// ---------------------------------------------------------------------------
// dt_proj fp16 MFMA + softplus -> delta16 (verified r14)
// ---------------------------------------------------------------------------
__global__ __launch_bounds__(256)
void dtproj_f16_kernel(const float* __restrict__ xdbl, const _Float16* __restrict__ dw16,
                       const float* __restrict__ bcat, _Float16* __restrict__ delta16)
{
    __shared__ __align__(16) _Float16 Asw[128 * 64];
    __shared__ __align__(16) _Float16 Bsw[128 * 64];
    const int t = threadIdx.x, wid = t >> 6, lane = t & 63;
    const int wm = wid >> 1, wn = wid & 1;
    const int n0 = blockIdx.x * 128, m0 = blockIdx.y * 128;
    const int dirb = blockIdx.z, dir = dirb >> 1;
    const float* Xb = xdbl + (long)dirb * 96 * 1024;
    const _Float16* Bw = dw16 + (long)dir * 2048 * 64;
    const int srow = lane >> 3, skk = ((lane & 7) ^ srow) * 8;
    const int lloc = (t & 31) * 4, kslt = t >> 5;

#pragma unroll
    for (int c = wid; c < 16; c += 4)
        gload_lds16(Bw + (long)(n0 + c * 8 + srow) * 64 + skk, Bsw + c * 512);
    float av[8][4];
#pragma unroll
    for (int kk = 0; kk < 8; ++kk) {
        f32x4 v = *(const f32x4*)&Xb[(long)(kslt * 8 + kk) * 1024 + m0 + lloc];
        av[kk][0] = v.x; av[kk][1] = v.y; av[kk][2] = v.z; av[kk][3] = v.w;
    }
#pragma unroll
    for (int q = 0; q < 4; ++q) {
        int l = lloc + q;
        f16x8 h = {(_Float16)av[0][q], (_Float16)av[1][q], (_Float16)av[2][q],
                   (_Float16)av[3][q], (_Float16)av[4][q], (_Float16)av[5][q],
                   (_Float16)av[6][q], (_Float16)av[7][q]};
        *(f16x8*)(Asw + l * 64 + ((kslt ^ (l & 7)) * 8)) = h;
    }
    __syncthreads();

    f32x4 acc[4][4];
#pragma unroll
    for (int i = 0; i < 4; ++i)
#pragma unroll
        for (int j = 0; j < 4; ++j) acc[i][j] = (f32x4){0.f, 0.f, 0.f, 0.f};
#pragma unroll
    for (int kw = 0; kw < 2; ++kw) {
        f16x8 af[4], bf[4];
#pragma unroll
        for (int i = 0; i < 4; ++i) {
            int r = wm * 64 + i * 16 + (lane & 15);
            af[i] = *(const f16x8*)(Asw + r * 64 +
                    (((kw * 4 + (lane >> 4)) ^ (r & 7)) * 8));
        }
#pragma unroll
        for (int j = 0; j < 4; ++j) {
            int r = wn * 64 + j * 16 + (lane & 15);
            bf[j] = *(const f16x8*)(Bsw + r * 64 +
                    (((kw * 4 + (lane >> 4)) ^ (r & 7)) * 8));
        }
#pragma unroll
        for (int i = 0; i < 4; ++i)
#pragma unroll
            for (int j = 0; j < 4; ++j)
                acc[i][j] = __builtin_amdgcn_mfma_f32_16x16x32_f16(
                    af[i], bf[j], acc[i][j], 0, 0, 0);
    }
    _Float16* Dp = delta16 + (long)dirb * 2048 * 1024;
#pragma unroll
    for (int j = 0; j < 4; ++j) {
        int dd = n0 + wn * 64 + j * 16 + (lane & 15);
        float bm = bcat[dir * 2048 + dd];
#pragma unroll
        for (int i = 0; i < 4; ++i) {
            int m = m0 + wm * 64 + i * 16 + (lane >> 4) * 4;
            f32x4 v = acc[i][j];
            f16x4 o = {(_Float16)softplus_f(v.x + bm), (_Float16)softplus_f(v.y + bm),
                       (_Float16)softplus_f(v.z + bm), (_Float16)softplus_f(v.w + bm)};
            *(f16x4*)&Dp[(long)dd * 1024 + m] = o;
        }
    }
}

// Merged setup (verified r14).
__global__ __launch_bounds__(256)
void setup_kernel(const float* __restrict__ hidden, const float* __restrict__ winp,
                  const float* __restrict__ woutp,
                  const float* __restrict__ xwf, const float* __restrict__ xwb,
                  const float* __restrict__ dwf, const float* __restrict__ dwb,
                  const float* __restrict__ bf,  const float* __restrict__ bb,
                  _Float16* __restrict__ H16, _Float16* __restrict__ Win16,
                  _Float16* __restrict__ Wout16,
                  _Float16* __restrict__ xw16, _Float16* __restrict__ dw16,
                  float* __restrict__ bcat)
{
    long i4 = ((long)blockIdx.x * 256 + threadIdx.x) * 4;
    auto cvt4 = [](const float* s) -> f16x4 {
        float4 v = *(const float4*)s;
        return (f16x4){(_Float16)v.x, (_Float16)v.y, (_Float16)v.z, (_Float16)v.w};
    };
    if (i4 < 4194304) *(f16x4*)(Win16 + i4) = cvt4(winp + i4);
    if (i4 < 2097152) {
        *(f16x4*)(H16 + i4)   = cvt4(hidden + i4);
        *(f16x4*)(Wout16 + i4) = cvt4(woutp + i4);
    }
    if (i4 < 196608) {
        *(f16x4*)(xw16 + i4)          = cvt4(xwf + i4);
        *(f16x4*)(xw16 + 196608 + i4) = cvt4(xwb + i4);
    }
    if (i4 < 131072) {
        *(f16x4*)(dw16 + i4)          = cvt4(dwf + i4);
        *(f16x4*)(dw16 + 131072 + i4) = cvt4(dwb + i4);
    }
    if (i4 < 2048) {
        *(float4*)(bcat + i4)        = *(const float4*)(bf + i4);
        *(float4*)(bcat + 2048 + i4) = *(const float4*)(bb + i4);
    }
}

// Depthwise causal conv (k=4) + SiLU -> u16; reads fp16 xz.
__global__ __launch_bounds__(256)
void conv_silu_kernel(const _Float16* __restrict__ xz16,
                      const float* __restrict__ wf, const float* __restrict__ bf,
                      const float* __restrict__ wb, const float* __restrict__ bbk,
                      _Float16* __restrict__ u16)
{
    long idx = (long)blockIdx.x * 256 + threadIdx.x;
    int l = (int)(idx & 1023);
    long r = idx >> 10;
    int d = (int)(r & 2047);
    int b = (int)((r >> 11) & 1);
    int dir = (int)(r >> 12);
    const _Float16* x = xz16 + ((long)b * 4096 + d) * 1024;
    const float* w = dir ? wb : wf;
    float s = dir ? bbk[d] : bf[d];
    if (dir == 0) {
#pragma unroll
        for (int j = 0; j < 4; ++j) {
            int p = l - 3 + j;
            if (p >= 0) s = fmaf(w[d * 4 + j], (float)x[p], s);
        }
    } else {
#pragma unroll
        for (int j = 0; j < 4; ++j) {
            int src = l - 3 + j;
            if (src >= 0) s = fmaf(w[d * 4 + j], (float)x[1023 - src], s);
        }
    }
    u16[idx] = (_Float16)(s / (1.f + __builtin_amdgcn_exp2f(-s * 1.44269504f)));
}

// ---------------------------------------------------------------------------
// scan pass 1: per-chunk local scan -> hend16/aprod16 (verified r16).
// ---------------------------------------------------------------------------
__global__ __launch_bounds__(256)
void scan_p1_kernel(const _Float16* __restrict__ u16, const _Float16* __restrict__ delta16,
                    const float* __restrict__ xdbl,
                    const float* __restrict__ Alf, const float* __restrict__ Alb,
                    _Float16* __restrict__ hend16, _Float16* __restrict__ aprod16)
{
    __shared__ _Float16 sD[64][40], sU[64][40];
    __shared__ float sB[32][20];
    const int t = threadIdx.x, wid = t >> 6, lane = t & 63;
    const int nl = lane & 3;
    const int dloc = wid * 16 + (lane >> 2);
    const int dblk = blockIdx.x, chunk = blockIdx.y, dirb = blockIdx.z;
    const int d = dblk * 64 + dloc, dir = dirb >> 1;
    const int T0 = chunk * SCL;
    f32x4 Av = *(const f32x4*)((dir ? Alb : Alf) + d * 16 + nl * 4);
    float An2[4] = {-expf(Av.x) * 1.44269504f, -expf(Av.y) * 1.44269504f,
                    -expf(Av.z) * 1.44269504f, -expf(Av.w) * 1.44269504f};
    const _Float16* dp = delta16 + ((long)dirb * 2048 + dblk * 64) * 1024;
    const _Float16* up = u16    + ((long)dirb * 2048 + dblk * 64) * 1024;
    const float* Bp = xdbl + ((long)dirb * 96 + 64) * 1024;

    {
        int dd = t >> 2, q = t & 3;
        *(f16x8*)&sD[dd][q * 8] = *(const f16x8*)&dp[(long)dd * 1024 + T0 + q * 8];
        *(f16x8*)&sU[dd][q * 8] = *(const f16x8*)&up[(long)dd * 1024 + T0 + q * 8];
    }
#pragma unroll
    for (int rep = 0; rep < 2; ++rep) {
        int ii = rep * 256 + t;
        int n = ii >> 5, tt = ii & 31;
        sB[tt][n] = Bp[(long)n * 1024 + T0 + tt];
    }
    __syncthreads();

    float h[4] = {0.f, 0.f, 0.f, 0.f};
    float S = 0.f;
#pragma unroll 4
    for (int g = 0; g < 8; ++g) {
        f16x4 dlh = *(const f16x4*)&sD[dloc][g * 4];
        f16x4 uuh = *(const f16x4*)&sU[dloc][g * 4];
        float dls[4] = {(float)dlh[0], (float)dlh[1], (float)dlh[2], (float)dlh[3]};
        float uus[4] = {(float)uuh[0], (float)uuh[1], (float)uuh[2], (float)uuh[3]};
#pragma unroll
        for (int r4 = 0; r4 < 4; ++r4) {
            f32x4 Bv = *(const f32x4*)&sB[g * 4 + r4][nl * 4];
            float Bs[4] = {Bv.x, Bv.y, Bv.z, Bv.w};
            float dl = dls[r4], t1 = dl * uus[r4];
            S += dl;
#pragma unroll
            for (int r = 0; r < 4; ++r)
                h[r] = fmaf(__builtin_amdgcn_exp2f(dl * An2[r]), h[r], t1 * Bs[r]);
        }
    }
    long cb = (((long)dirb * SCH + chunk) * 2048 + d) * 16 + nl * 4;
    f16x4 he = {(_Float16)h[0], (_Float16)h[1], (_Float16)h[2], (_Float16)h[3]};
    f16x4 ap = {(_Float16)__builtin_amdgcn_exp2f(S * An2[0]),
                (_Float16)__builtin_amdgcn_exp2f(S * An2[1]),
                (_Float16)__builtin_amdgcn_exp2f(S * An2[2]),
                (_Float16)__builtin_amdgcn_exp2f(S * An2[3])};
    *(f16x4*)&hend16[cb]  = he;
    *(f16x4*)&aprod16[cb] = ap;
}

// scan pass 2: sequential carry combine (f32 in-register, fp16 storage).
__global__ __launch_bounds__(256)
void scan_carry_kernel(const _Float16* __restrict__ hend16,
                       const _Float16* __restrict__ aprod16,
                       _Float16* __restrict__ hinit16)
{
    int f = blockIdx.x * 256 + threadIdx.x;   // (dirb, d*16+n)
    int dn = f & 32767;
    int dirb = f >> 15;
    long base = (long)dirb * SCH * 32768 + dn;
    float hcur = 0.f;
#pragma unroll
    for (int c = 0; c < SCH; ++c) {
        hinit16[base + (long)c * 32768] = (_Float16)hcur;
        hcur = (float)hend16[base + (long)c * 32768]
             + (float)aprod16[base + (long)c * 32768] * hcur;
    }
}

// ---------------------------------------------------------------------------
// scan pass 3 FUSED with combine (verified r18): block = (dblk, c, b) handles
// dir0 chunk c and dir1 chunk 31-c for 64 d's. Emits GT[b][l][d] fp16.
// ---------------------------------------------------------------------------
__global__ __launch_bounds__(256)
void scan_p3c_kernel(const _Float16* __restrict__ u16, const _Float16* __restrict__ delta16,
                     const float* __restrict__ xdbl,
                     const float* __restrict__ Alf, const float* __restrict__ Alb,
                     const float* __restrict__ Df, const float* __restrict__ Db,
                     const _Float16* __restrict__ hinit16,
                     const _Float16* __restrict__ xz16,
                     _Float16* __restrict__ GT)
{
    __shared__ _Float16 sDf[64][40], sUf[64][40], sDb[64][40], sUb[64][40];
    __shared__ float sBf[32][20], sCf[32][20], sBb[32][20], sCb[32][20];
    __shared__ _Float16 sYf[64][40], sYb[64][40];
    const int t = threadIdx.x, wid = t >> 6, lane = t & 63;
    const int nl = lane & 3;
    const int dloc = wid * 16 + (lane >> 2);
    const int dblk = blockIdx.x, c = blockIdx.y, b = blockIdx.z;
    const int d = dblk * 64 + dloc;
    const int cB = SCH - 1 - c;
    const int T0f = c * SCL, T0b = cB * SCL;
    const int dirbF = b, dirbB = 2 + b;

    f32x4 AvF = *(const f32x4*)(Alf + d * 16 + nl * 4);
    f32x4 AvB = *(const f32x4*)(Alb + d * 16 + nl * 4);
    float AnF[4] = {-expf(AvF.x) * 1.44269504f, -expf(AvF.y) * 1.44269504f,
                    -expf(AvF.z) * 1.44269504f, -expf(AvF.w) * 1.44269504f};
    float AnB[4] = {-expf(AvB.x) * 1.44269504f, -expf(AvB.y) * 1.44269504f,
                    -expf(AvB.z) * 1.44269504f, -expf(AvB.w) * 1.44269504f};
    const float DdF = Df[d], DdB = Db[d];
    const _Float16* dpF = delta16 + ((long)dirbF * 2048 + dblk * 64) * 1024;
    const _Float16* upF = u16    + ((long)dirbF * 2048 + dblk * 64) * 1024;
    const _Float16* dpB = delta16 + ((long)dirbB * 2048 + dblk * 64) * 1024;
    const _Float16* upB = u16    + ((long)dirbB * 2048 + dblk * 64) * 1024;
    const float* BpF = xdbl + ((long)dirbF * 96 + 64) * 1024;
    const float* CpF = xdbl + ((long)dirbF * 96 + 80) * 1024;
    const float* BpB = xdbl + ((long)dirbB * 96 + 64) * 1024;
    const float* CpB = xdbl + ((long)dirbB * 96 + 80) * 1024;

    {   // stage D/U for both dirs
        int dd = t >> 2, q = t & 3;
        *(f16x8*)&sDf[dd][q * 8] = *(const f16x8*)&dpF[(long)dd * 1024 + T0f + q * 8];
        *(f16x8*)&sUf[dd][q * 8] = *(const f16x8*)&upF[(long)dd * 1024 + T0f + q * 8];
        *(f16x8*)&sDb[dd][q * 8] = *(const f16x8*)&dpB[(long)dd * 1024 + T0b + q * 8];
        *(f16x8*)&sUb[dd][q * 8] = *(const f16x8*)&upB[(long)dd * 1024 + T0b + q * 8];
    }
#pragma unroll
    for (int rep = 0; rep < 2; ++rep) {
        int ii = rep * 256 + t;
        int n = ii >> 5, tt = ii & 31;
        sBf[tt][n] = BpF[(long)n * 1024 + T0f + tt];
        sCf[tt][n] = CpF[(long)n * 1024 + T0f + tt];
        sBb[tt][n] = BpB[(long)n * 1024 + T0b + tt];
        sCb[tt][n] = CpB[(long)n * 1024 + T0b + tt];
    }
    long cbF = (((long)dirbF * SCH + c)  * 2048 + d) * 16 + nl * 4;
    long cbB = (((long)dirbB * SCH + cB) * 2048 + d) * 16 + nl * 4;
    f16x4 h0F = *(const f16x4*)&hinit16[cbF];
    f16x4 h0B = *(const f16x4*)&hinit16[cbB];
    const bool m[4] = {nl == 0, nl == 1, nl == 2, nl == 3};
    __syncthreads();

    // dir0 recurrence -> sYf[dloc][li]
    {
        float h[4] = {(float)h0F[0], (float)h0F[1], (float)h0F[2], (float)h0F[3]};
#pragma unroll 4
        for (int g = 0; g < 8; ++g) {
            f16x4 dlh = *(const f16x4*)&sDf[dloc][g * 4];
            f16x4 uuh = *(const f16x4*)&sUf[dloc][g * 4];
            float dls[4] = {(float)dlh[0], (float)dlh[1], (float)dlh[2], (float)dlh[3]};
            float uus[4] = {(float)uuh[0], (float)uuh[1], (float)uuh[2], (float)uuh[3]};
            float keep = 0.f;
#pragma unroll
            for (int r4 = 0; r4 < 4; ++r4) {
                f32x4 Bv = *(const f32x4*)&sBf[g * 4 + r4][nl * 4];
                f32x4 Cv = *(const f32x4*)&sCf[g * 4 + r4][nl * 4];
                float dl = dls[r4], uu = uus[r4], t1 = dl * uu;
#pragma unroll
                for (int r = 0; r < 4; ++r)
                    h[r] = fmaf(__builtin_amdgcn_exp2f(dl * AnF[r]), h[r],
                                t1 * ((const float*)&Bv)[r]);
                float p = h[0] * Cv.x;
                p = fmaf(h[1], Cv.y, p);
                p = fmaf(h[2], Cv.z, p);
                p = fmaf(h[3], Cv.w, p);
                p = dpp_add<0xB1>(p);
                p = dpp_add<0x4E>(p);
                float fy = fmaf(DdF, uu, p);
                keep = m[r4] ? fy : keep;
            }
            sYf[dloc][g * 4 + nl] = (_Float16)keep;
        }
    }
    // dir1 recurrence -> sYb[dloc][31 - li]
    {
        float h[4] = {(float)h0B[0], (float)h0B[1], (float)h0B[2], (float)h0B[3]};
#pragma unroll 4
        for (int g = 0; g < 8; ++g) {
            f16x4 dlh = *(const f16x4*)&sDb[dloc][g * 4];
            f16x4 uuh = *(const f16x4*)&sUb[dloc][g * 4];
            float dls[4] = {(float)dlh[0], (float)dlh[1], (float)dlh[2], (float)dlh[3]};
            float uus[4] = {(float)uuh[0], (float)uuh[1], (float)uuh[2], (float)uuh[3]};
            float keep = 0.f;
#pragma unroll
            for (int r4 = 0; r4 < 4; ++r4) {
                f32x4 Bv = *(const f32x4*)&sBb[g * 4 + r4][nl * 4];
                f32x4 Cv = *(const f32x4*)&sCb[g * 4 + r4][nl * 4];
                float dl = dls[r4], uu = uus[r4], t1 = dl * uu;
#pragma unroll
                for (int r = 0; r < 4; ++r)
                    h[r] = fmaf(__builtin_amdgcn_exp2f(dl * AnB[r]), h[r],
                                t1 * ((const float*)&Bv)[r]);
                float p = h[0] * Cv.x;
                p = fmaf(h[1], Cv.y, p);
                p = fmaf(h[2], Cv.z, p);
                p = fmaf(h[3], Cv.w, p);
                p = dpp_add<0xB1>(p);
                p = dpp_add<0x4E>(p);
                float fy = fmaf(DdB, uu, p);
                keep = m[r4] ? fy : keep;
            }
            sYb[dloc][31 - (g * 4 + nl)] = (_Float16)keep;
        }
    }
    __syncthreads();

    // combine (reuse sDf as G buffer)
    {
        int dd = t >> 2, lq = (t & 3) * 8;
        f16x8 vz = *(const f16x8*)&xz16[((long)b * 4096 + 2048 + dblk * 64 + dd) * 1024
                                        + T0f + lq];
#pragma unroll
        for (int j = 0; j < 8; ++j) {
            float z = (float)vz[j];
            float sz = z / (1.f + __builtin_amdgcn_exp2f(-z * 1.44269504f));
            float g = sz * ((float)sYf[dd][lq + j] + (float)sYb[dd][lq + j]);
            sDf[dd][lq + j] = (_Float16)g;
        }
    }
    __syncthreads();

    // transpose-write GT[b][T0f+ll][dblk*64 + dq..dq+3]
#pragma unroll
    for (int rep = 0; rep < 2; ++rep) {
        int ii = rep * 256 + t;
        int ll = ii >> 4;
        int dq = (ii & 15) * 4;
        f16x4 h = {sDf[dq][ll], sDf[dq + 1][ll], sDf[dq + 2][ll], sDf[dq + 3][ll]};
        *(f16x4*)(GT + ((long)(b * 1024 + T0f + ll)) * 2048 + dblk * 64 + dq) = h;
    }
}

extern "C" void kernel_launch(void* const* d_in, const int* in_sizes, int n_in,
                              void* d_out, int out_size, void* d_ws, size_t ws_size,
                              hipStream_t stream)
{
    const float* hidden   = (const float*)d_in[0];
    const float* inproj_w = (const float*)d_in[1];
    const float* conv_w   = (const float*)d_in[2];
    const float* conv_b   = (const float*)d_in[3];
    const float* xproj_w  = (const float*)d_in[4];
    const float* dtproj_w = (const float*)d_in[5];
    const float* dt_bias  = (const float*)d_in[6];
    const float* A_log    = (const float*)d_in[7];
    const float* D_skip   = (const float*)d_in[8];
    const float* convb_w  = (const float*)d_in[9];
    const float* convb_b  = (const float*)d_in[10];
    const float* xprojb_w = (const float*)d_in[11];
    const float* dtprojb_w= (const float*)d_in[12];
    const float* dtb_bias = (const float*)d_in[13];
    const float* Ab_log   = (const float*)d_in[14];
    const float* Db_skip  = (const float*)d_in[15];
    const float* outproj_w= (const float*)d_in[16];
    float* out = (float*)d_out;

    float* ws    = (float*)d_ws;
    float* xz    = ws;
    float* u     = ws + 8388608;
    float* xdbl  = ws + 16777216;
    float* delta = ws + 17170432;
    float* y     = ws + 25559040;
    // xz region: fp16 xz (dead after p3c)
    _Float16* xz16  = (_Float16*)xz;
    // u region: H16 | Win16 | u16 | Wout16; hinit16 overlays H16/Win16 later
    _Float16* H16     = (_Float16*)u;
    _Float16* Win16   = (_Float16*)(u + 1048576);
    _Float16* u16     = (_Float16*)(u + 3145728);
    _Float16* Wout16  = (_Float16*)(u + 7340032);
    _Float16* hinit16 = (_Float16*)u;
    // delta region: delta16 | xpb partials
    _Float16* delta16 = (_Float16*)delta;
    float*    xpb     = delta + 4194304;
    // y region: scratch -> hend16|aprod16 (dead after carry) -> GT
    _Float16* dw16  = (_Float16*)y;
    float*    bcat  = y + 131072;
    _Float16* xw16  = (_Float16*)(y + 135168);
    _Float16* hend16  = (_Float16*)y;
    _Float16* aprod16 = (_Float16*)(y + 2097152);
    _Float16* GT      = (_Float16*)y;              // [0, 2.1M f32) after carry

    // 0) merged setup
    hipLaunchKernelGGL(setup_kernel, dim3(4096), dim3(256), 0, stream,
        hidden, inproj_w, outproj_w, xproj_w, xprojb_w, dtproj_w, dtprojb_w,
        dt_bias, dtb_bias, H16, Win16, Wout16, xw16, dw16, bcat);

    // 1) in_proj MFMA -> fp16 xz
    hipLaunchKernelGGL((gemm_nt_f16<2, 2, 2, 4, _Float16>),
        dim3(32, 16, 2), dim3(256), 0, stream,
        H16, Win16, xz16, 1024, 1024, 1024, 1048576L, 0L, 4194304L);

    // 2) conv + silu -> u16
    hipLaunchKernelGGL(conv_silu_kernel, dim3(32768), dim3(256), 0, stream,
        xz16, conv_w, conv_b, convb_w, convb_b, u16);

    // 3) x_proj MFMA split-K + reduce
    hipLaunchKernelGGL(xproj_f16_kernel, dim3(8, XP_SK, 4), dim3(256), 0, stream,
        u16, xw16, xpb);
    hipLaunchKernelGGL(xreduce_kernel, dim3(384), dim3(256), 0, stream,
        xpb, xdbl);

    // 4) dt_proj fp16 MFMA + softplus -> delta16
    hipLaunchKernelGGL(dtproj_f16_kernel, dim3(16, 8, 4), dim3(256), 0, stream,
        xdbl, dw16, bcat, delta16);

    // 5) scan: p1 -> carry -> fused p3+combine (emits GT)
    hipLaunchKernelGGL(scan_p1_kernel, dim3(32, SCH, 4), dim3(256), 0, stream,
        u16, delta16, xdbl, A_log, Ab_log, hend16, aprod16);
    hipLaunchKernelGGL(scan_carry_kernel, dim3(512), dim3(256), 0, stream,
        hend16, aprod16, hinit16);
    hipLaunchKernelGGL(scan_p3c_kernel, dim3(32, SCH, 2), dim3(256), 0, stream,
        u16, delta16, xdbl, A_log, Ab_log, D_skip, Db_skip, hinit16, xz16, GT);

    // 6) out_proj MFMA direct: out[(b,l)][o], K=2048
    hipLaunchKernelGGL((gemm_nt_f16<4, 1, 2, 4, float>),
        dim3(32, 8, 1), dim3(256), 0, stream,
        Wout16, GT, out, 2048, 2048, 1024, 0L, 0L, 0L);
}

// Round 21
// 172.933 us; speedup vs baseline: 1.0402x; 1.0402x over previous
//
#include <hip/hip_runtime.h>
#include <math.h>

// ---------------------------------------------------------------------------
// Bidirectional Mamba block, MI355X. Round 21:
//  - restore r18 launch config (out_proj split-K=2 + oreduce; r20 showed
//    de-split regresses 173.4->179.9 with p3c in place).
//  - p3c v2: y values in REGISTERS during recurrence; sY/sG alias dead
//    staging LDS after one barrier -> 41->30KB LDS (5 blk/CU); sY/sG
//    stride 42 kills the 8-way transpose bank conflict (word-stride
//    84%32=20 -> 2-way ~ free).
// ws layout (f32 elements):
//   xz    region: xz16 fp16 (dead after p3c) -> opart f32 [2][2048][1024]
//   u     region: [0,2.1M) H16+Win16 -> hinit16 | [3M,7M) u16 | [7M,8M) Wout16
//   xdbl  [dirb][96][1024] f32
//   delta region: [0,4.2M) delta16 | [4.2M,7.3M) xpb partials
//   y     region: scratch -> hend16|aprod16 (dead after carry) -> GT [0,2.1M)
// ---------------------------------------------------------------------------

typedef _Float16 f16x8 __attribute__((ext_vector_type(8)));
typedef _Float16 f16x4 __attribute__((ext_vector_type(4)));
typedef float    f32x4 __attribute__((ext_vector_type(4)));

#define SCH 32    // scan chunks
#define SCL 32    // chunk length

__device__ __forceinline__ void gload_lds16(const void* g, void* l) {
    __builtin_amdgcn_global_load_lds(
        (const __attribute__((address_space(1))) void*)g,
        (__attribute__((address_space(3))) void*)l, 16, 0, 0);
}

__device__ __forceinline__ float softplus_f(float x) {
    float e = __builtin_amdgcn_exp2f(-fabsf(x) * 1.44269504f);
    return fmaxf(x, 0.f) + __builtin_amdgcn_logf(1.f + e) * 0.69314718f;
}

template<int CTRL>
__device__ __forceinline__ float dpp_add(float x) {
    int s = __builtin_amdgcn_update_dpp(0, __builtin_bit_cast(int, x),
                                        CTRL, 0xF, 0xF, true);
    return x + __builtin_bit_cast(float, s);
}

// ---------------------------------------------------------------------------
// fp16 NT MFMA GEMM (verified r17). z-dim: A += z*sA, B += z*sB, C += z*sC.
// ---------------------------------------------------------------------------
template<int WMW, int WNW, int FM, int FN, typename CT>
__global__ __launch_bounds__(256)
void gemm_nt_f16(const _Float16* __restrict__ A, const _Float16* __restrict__ B,
                 CT* __restrict__ C, int K, int lda, int ldc,
                 long sA, long sB, long sC)
{
    constexpr int BM = WMW * FM * 16, BN = WNW * FN * 16;
    constexpr int ACH = BM / 8, NCH = (BM + BN) / 8;
    __shared__ __align__(16) _Float16 lds[(BM + BN) * 64];
    A += (long)blockIdx.z * sA;
    B += (long)blockIdx.z * sB;
    C += (long)blockIdx.z * sC;
    const int m0 = blockIdx.y * BM, n0 = blockIdx.x * BN;
    const int t = threadIdx.x, wid = t >> 6, lane = t & 63;
    const int wm = wid / WNW, wn = wid % WNW;
    const int srow = lane >> 3;
    const int skk  = ((lane & 7) ^ srow) * 8;

    f32x4 acc[FM][FN];
#pragma unroll
    for (int i = 0; i < FM; ++i)
#pragma unroll
        for (int j = 0; j < FN; ++j) acc[i][j] = (f32x4){0.f, 0.f, 0.f, 0.f};

    for (int k0 = 0; k0 < K; k0 += 64) {
#pragma unroll
        for (int c = wid; c < NCH; c += 4) {
            const _Float16* gp = (c < ACH)
                ? A + (long)(m0 + c * 8 + srow) * lda + k0 + skk
                : B + (long)(n0 + (c - ACH) * 8 + srow) * lda + k0 + skk;
            gload_lds16(gp, lds + c * 512);
        }
        __syncthreads();
#pragma unroll
        for (int kw = 0; kw < 2; ++kw) {
            f16x8 af[FM], bf[FN];
#pragma unroll
            for (int i = 0; i < FM; ++i) {
                int r = wm * FM * 16 + i * 16 + (lane & 15);
                af[i] = *(const f16x8*)(lds + r * 64 +
                        (((kw * 4 + (lane >> 4)) ^ (r & 7)) * 8));
            }
#pragma unroll
            for (int j = 0; j < FN; ++j) {
                int r = wn * FN * 16 + j * 16 + (lane & 15);
                bf[j] = *(const f16x8*)(lds + BM * 64 + r * 64 +
                        (((kw * 4 + (lane >> 4)) ^ (r & 7)) * 8));
            }
#pragma unroll
            for (int i = 0; i < FM; ++i)
#pragma unroll
                for (int j = 0; j < FN; ++j)
                    acc[i][j] = __builtin_amdgcn_mfma_f32_16x16x32_f16(
                        af[i], bf[j], acc[i][j], 0, 0, 0);
        }
        __syncthreads();
    }
#pragma unroll
    for (int i = 0; i < FM; ++i)
#pragma unroll
        for (int j = 0; j < FN; ++j) {
            int n = n0 + wn * FN * 16 + j * 16 + (lane & 15);
            int m = m0 + wm * FM * 16 + i * 16 + (lane >> 4) * 4;
            f32x4 v = acc[i][j];
            if constexpr (__is_same(CT, float)) {
                *(f32x4*)&C[(long)n * ldc + m] = v;
            } else {
                f16x4 h = {(_Float16)v.x, (_Float16)v.y, (_Float16)v.z, (_Float16)v.w};
                *(f16x4*)&C[(long)n * ldc + m] = h;
            }
        }
}

// out = p0 + p1 (out_proj split-K reduce)
__global__ __launch_bounds__(256)
void oreduce_kernel(const float* __restrict__ p, float* __restrict__ out)
{
    int f = (blockIdx.x * 256 + threadIdx.x) * 4;
    f32x4 a = *(const f32x4*)(p + f);
    f32x4 b = *(const f32x4*)(p + 2097152 + f);
    *(f32x4*)(out + f) = a + b;
}

// ---------------------------------------------------------------------------
// x_proj fp16 MFMA, split-K (verified r8/r14).
// ---------------------------------------------------------------------------
#define XP_SK 8
__global__ __launch_bounds__(256)
void xproj_f16_kernel(const _Float16* __restrict__ u16, const _Float16* __restrict__ xw16,
                      float* __restrict__ pb)
{
    __shared__ __align__(16) _Float16 Asw[128 * 64];
    __shared__ __align__(16) _Float16 Bsw[96 * 64];
    const int t = threadIdx.x, wid = t >> 6, lane = t & 63;
    const int wm = wid >> 1, wn = wid & 1;
    const int m0 = blockIdx.x * 128;
    const int sk = blockIdx.y, dirb = blockIdx.z;
    const _Float16* ub = u16 + (long)dirb * 2048 * 1024;
    const _Float16* Bw = xw16 + (long)(dirb >> 1) * 96 * 2048;
    const int srow = lane >> 3;
    const int skk  = ((lane & 7) ^ srow) * 8;
    const int lloc = (t & 31) * 4;
    const int kslt = t >> 5;

    f32x4 acc[4][3];
#pragma unroll
    for (int i = 0; i < 4; ++i)
#pragma unroll
        for (int j = 0; j < 3; ++j) acc[i][j] = (f32x4){0.f, 0.f, 0.f, 0.f};

    for (int ks = 0; ks < 2048 / XP_SK; ks += 64) {
        const int k0 = sk * (2048 / XP_SK) + ks;
#pragma unroll
        for (int c = wid; c < 12; c += 4)
            gload_lds16(Bw + (long)(c * 8 + srow) * 2048 + k0 + skk, Bsw + c * 512);
        _Float16 av[8][4];
#pragma unroll
        for (int kk = 0; kk < 8; ++kk) {
            f16x4 v = *(const f16x4*)&ub[(long)(k0 + kslt * 8 + kk) * 1024 + m0 + lloc];
            av[kk][0] = v[0]; av[kk][1] = v[1]; av[kk][2] = v[2]; av[kk][3] = v[3];
        }
#pragma unroll
        for (int q = 0; q < 4; ++q) {
            int l = lloc + q;
            f16x8 h = {av[0][q], av[1][q], av[2][q], av[3][q],
                       av[4][q], av[5][q], av[6][q], av[7][q]};
            *(f16x8*)(Asw + l * 64 + ((kslt ^ (l & 7)) * 8)) = h;
        }
        __syncthreads();
#pragma unroll
        for (int kw = 0; kw < 2; ++kw) {
            f16x8 af[4], bf[3];
#pragma unroll
            for (int i = 0; i < 4; ++i) {
                int r = wm * 64 + i * 16 + (lane & 15);
                af[i] = *(const f16x8*)(Asw + r * 64 +
                        (((kw * 4 + (lane >> 4)) ^ (r & 7)) * 8));
            }
#pragma unroll
            for (int j = 0; j < 3; ++j) {
                int r = wn * 48 + j * 16 + (lane & 15);
                bf[j] = *(const f16x8*)(Bsw + r * 64 +
                        (((kw * 4 + (lane >> 4)) ^ (r & 7)) * 8));
            }
#pragma unroll
            for (int i = 0; i < 4; ++i)
#pragma unroll
                for (int j = 0; j < 3; ++j)
                    acc[i][j] = __builtin_amdgcn_mfma_f32_16x16x32_f16(
                        af[i], bf[j], acc[i][j], 0, 0, 0);
        }
        __syncthreads();
    }
    float* Cp = pb + ((long)sk * 4 + dirb) * 96 * 1024;
#pragma unroll
    for (int i = 0; i < 4; ++i)
#pragma unroll
        for (int j = 0; j < 3; ++j) {
            int n = wn * 48 + j * 16 + (lane & 15);
            int m = m0 + wm * 64 + i * 16 + (lane >> 4) * 4;
            *(f32x4*)&Cp[(long)n * 1024 + m] = acc[i][j];
        }
}

__global__ __launch_bounds__(256)
void xreduce_kernel(const float* __restrict__ pb, float* __restrict__ xdbl)
{
    int f = (blockIdx.x * 256 + threadIdx.x) * 4;
    f32x4 s = (f32x4){0.f, 0.f, 0.f, 0.f};
#pragma unroll
    for (int sk = 0; sk < XP_SK; ++sk)
        s += *(const f32x4*)(pb + (long)sk * 393216 + f);
    *(f32x4*)(xdbl + f) = s;
}

// ---------------------------------------------------------------------------
// dt_proj fp16 MFMA + softplus -> delta16 (verified r14)
// ---------------------------------------------------------------------------
__global__ __launch_bounds__(256)
void dtproj_f16_kernel(const float* __restrict__ xdbl, const _Float16* __restrict__ dw16,
                       const float* __restrict__ bcat, _Float16* __restrict__ delta16)
{
    __shared__ __align__(16) _Float16 Asw[128 * 64];
    __shared__ __align__(16) _Float16 Bsw[128 * 64];
    const int t = threadIdx.x, wid = t >> 6, lane = t & 63;
    const int wm = wid >> 1, wn = wid & 1;
    const int n0 = blockIdx.x * 128, m0 = blockIdx.y * 128;
    const int dirb = blockIdx.z, dir = dirb >> 1;
    const float* Xb = xdbl + (long)dirb * 96 * 1024;
    const _Float16* Bw = dw16 + (long)dir * 2048 * 64;
    const int srow = lane >> 3, skk = ((lane & 7) ^ srow) * 8;
    const int lloc = (t & 31) * 4, kslt = t >> 5;

#pragma unroll
    for (int c = wid; c < 16; c += 4)
        gload_lds16(Bw + (long)(n0 + c * 8 + srow) * 64 + skk, Bsw + c * 512);
    float av[8][4];
#pragma unroll
    for (int kk = 0; kk < 8; ++kk) {
        f32x4 v = *(const f32x4*)&Xb[(long)(kslt * 8 + kk) * 1024 + m0 + lloc];
        av[kk][0] = v.x; av[kk][1] = v.y; av[kk][2] = v.z; av[kk][3] = v.w;
    }
#pragma unroll
    for (int q = 0; q < 4; ++q) {
        int l = lloc + q;
        f16x8 h = {(_Float16)av[0][q], (_Float16)av[1][q], (_Float16)av[2][q],
                   (_Float16)av[3][q], (_Float16)av[4][q], (_Float16)av[5][q],
                   (_Float16)av[6][q], (_Float16)av[7][q]};
        *(f16x8*)(Asw + l * 64 + ((kslt ^ (l & 7)) * 8)) = h;
    }
    __syncthreads();

    f32x4 acc[4][4];
#pragma unroll
    for (int i = 0; i < 4; ++i)
#pragma unroll
        for (int j = 0; j < 4; ++j) acc[i][j] = (f32x4){0.f, 0.f, 0.f, 0.f};
#pragma unroll
    for (int kw = 0; kw < 2; ++kw) {
        f16x8 af[4], bf[4];
#pragma unroll
        for (int i = 0; i < 4; ++i) {
            int r = wm * 64 + i * 16 + (lane & 15);
            af[i] = *(const f16x8*)(Asw + r * 64 +
                    (((kw * 4 + (lane >> 4)) ^ (r & 7)) * 8));
        }
#pragma unroll
        for (int j = 0; j < 4; ++j) {
            int r = wn * 64 + j * 16 + (lane & 15);
            bf[j] = *(const f16x8*)(Bsw + r * 64 +
                    (((kw * 4 + (lane >> 4)) ^ (r & 7)) * 8));
        }
#pragma unroll
        for (int i = 0; i < 4; ++i)
#pragma unroll
            for (int j = 0; j < 4; ++j)
                acc[i][j] = __builtin_amdgcn_mfma_f32_16x16x32_f16(
                    af[i], bf[j], acc[i][j], 0, 0, 0);
    }
    _Float16* Dp = delta16 + (long)dirb * 2048 * 1024;
#pragma unroll
    for (int j = 0; j < 4; ++j) {
        int dd = n0 + wn * 64 + j * 16 + (lane & 15);
        float bm = bcat[dir * 2048 + dd];
#pragma unroll
        for (int i = 0; i < 4; ++i) {
            int m = m0 + wm * 64 + i * 16 + (lane >> 4) * 4;
            f32x4 v = acc[i][j];
            f16x4 o = {(_Float16)softplus_f(v.x + bm), (_Float16)softplus_f(v.y + bm),
                       (_Float16)softplus_f(v.z + bm), (_Float16)softplus_f(v.w + bm)};
            *(f16x4*)&Dp[(long)dd * 1024 + m] = o;
        }
    }
}

// Merged setup (verified r14).
__global__ __launch_bounds__(256)
void setup_kernel(const float* __restrict__ hidden, const float* __restrict__ winp,
                  const float* __restrict__ woutp,
                  const float* __restrict__ xwf, const float* __restrict__ xwb,
                  const float* __restrict__ dwf, const float* __restrict__ dwb,
                  const float* __restrict__ bf,  const float* __restrict__ bb,
                  _Float16* __restrict__ H16, _Float16* __restrict__ Win16,
                  _Float16* __restrict__ Wout16,
                  _Float16* __restrict__ xw16, _Float16* __restrict__ dw16,
                  float* __restrict__ bcat)
{
    long i4 = ((long)blockIdx.x * 256 + threadIdx.x) * 4;
    auto cvt4 = [](const float* s) -> f16x4 {
        float4 v = *(const float4*)s;
        return (f16x4){(_Float16)v.x, (_Float16)v.y, (_Float16)v.z, (_Float16)v.w};
    };
    if (i4 < 4194304) *(f16x4*)(Win16 + i4) = cvt4(winp + i4);
    if (i4 < 2097152) {
        *(f16x4*)(H16 + i4)   = cvt4(hidden + i4);
        *(f16x4*)(Wout16 + i4) = cvt4(woutp + i4);
    }
    if (i4 < 196608) {
        *(f16x4*)(xw16 + i4)          = cvt4(xwf + i4);
        *(f16x4*)(xw16 + 196608 + i4) = cvt4(xwb + i4);
    }
    if (i4 < 131072) {
        *(f16x4*)(dw16 + i4)          = cvt4(dwf + i4);
        *(f16x4*)(dw16 + 131072 + i4) = cvt4(dwb + i4);
    }
    if (i4 < 2048) {
        *(float4*)(bcat + i4)        = *(const float4*)(bf + i4);
        *(float4*)(bcat + 2048 + i4) = *(const float4*)(bb + i4);
    }
}

// Depthwise causal conv (k=4) + SiLU -> u16; reads fp16 xz.
__global__ __launch_bounds__(256)
void conv_silu_kernel(const _Float16* __restrict__ xz16,
                      const float* __restrict__ wf, const float* __restrict__ bf,
                      const float* __restrict__ wb, const float* __restrict__ bbk,
                      _Float16* __restrict__ u16)
{
    long idx = (long)blockIdx.x * 256 + threadIdx.x;
    int l = (int)(idx & 1023);
    long r = idx >> 10;
    int d = (int)(r & 2047);
    int b = (int)((r >> 11) & 1);
    int dir = (int)(r >> 12);
    const _Float16* x = xz16 + ((long)b * 4096 + d) * 1024;
    const float* w = dir ? wb : wf;
    float s = dir ? bbk[d] : bf[d];
    if (dir == 0) {
#pragma unroll
        for (int j = 0; j < 4; ++j) {
            int p = l - 3 + j;
            if (p >= 0) s = fmaf(w[d * 4 + j], (float)x[p], s);
        }
    } else {
#pragma unroll
        for (int j = 0; j < 4; ++j) {
            int src = l - 3 + j;
            if (src >= 0) s = fmaf(w[d * 4 + j], (float)x[1023 - src], s);
        }
    }
    u16[idx] = (_Float16)(s / (1.f + __builtin_amdgcn_exp2f(-s * 1.44269504f)));
}

// ---------------------------------------------------------------------------
// scan pass 1: per-chunk local scan -> hend16/aprod16 (verified r16).
// ---------------------------------------------------------------------------
__global__ __launch_bounds__(256)
void scan_p1_kernel(const _Float16* __restrict__ u16, const _Float16* __restrict__ delta16,
                    const float* __restrict__ xdbl,
                    const float* __restrict__ Alf, const float* __restrict__ Alb,
                    _Float16* __restrict__ hend16, _Float16* __restrict__ aprod16)
{
    __shared__ _Float16 sD[64][40], sU[64][40];
    __shared__ float sB[32][20];
    const int t = threadIdx.x, wid = t >> 6, lane = t & 63;
    const int nl = lane & 3;
    const int dloc = wid * 16 + (lane >> 2);
    const int dblk = blockIdx.x, chunk = blockIdx.y, dirb = blockIdx.z;
    const int d = dblk * 64 + dloc, dir = dirb >> 1;
    const int T0 = chunk * SCL;
    f32x4 Av = *(const f32x4*)((dir ? Alb : Alf) + d * 16 + nl * 4);
    float An2[4] = {-expf(Av.x) * 1.44269504f, -expf(Av.y) * 1.44269504f,
                    -expf(Av.z) * 1.44269504f, -expf(Av.w) * 1.44269504f};
    const _Float16* dp = delta16 + ((long)dirb * 2048 + dblk * 64) * 1024;
    const _Float16* up = u16    + ((long)dirb * 2048 + dblk * 64) * 1024;
    const float* Bp = xdbl + ((long)dirb * 96 + 64) * 1024;

    {
        int dd = t >> 2, q = t & 3;
        *(f16x8*)&sD[dd][q * 8] = *(const f16x8*)&dp[(long)dd * 1024 + T0 + q * 8];
        *(f16x8*)&sU[dd][q * 8] = *(const f16x8*)&up[(long)dd * 1024 + T0 + q * 8];
    }
#pragma unroll
    for (int rep = 0; rep < 2; ++rep) {
        int ii = rep * 256 + t;
        int n = ii >> 5, tt = ii & 31;
        sB[tt][n] = Bp[(long)n * 1024 + T0 + tt];
    }
    __syncthreads();

    float h[4] = {0.f, 0.f, 0.f, 0.f};
    float S = 0.f;
#pragma unroll 4
    for (int g = 0; g < 8; ++g) {
        f16x4 dlh = *(const f16x4*)&sD[dloc][g * 4];
        f16x4 uuh = *(const f16x4*)&sU[dloc][g * 4];
        float dls[4] = {(float)dlh[0], (float)dlh[1], (float)dlh[2], (float)dlh[3]};
        float uus[4] = {(float)uuh[0], (float)uuh[1], (float)uuh[2], (float)uuh[3]};
#pragma unroll
        for (int r4 = 0; r4 < 4; ++r4) {
            f32x4 Bv = *(const f32x4*)&sB[g * 4 + r4][nl * 4];
            float Bs[4] = {Bv.x, Bv.y, Bv.z, Bv.w};
            float dl = dls[r4], t1 = dl * uus[r4];
            S += dl;
#pragma unroll
            for (int r = 0; r < 4; ++r)
                h[r] = fmaf(__builtin_amdgcn_exp2f(dl * An2[r]), h[r], t1 * Bs[r]);
        }
    }
    long cb = (((long)dirb * SCH + chunk) * 2048 + d) * 16 + nl * 4;
    f16x4 he = {(_Float16)h[0], (_Float16)h[1], (_Float16)h[2], (_Float16)h[3]};
    f16x4 ap = {(_Float16)__builtin_amdgcn_exp2f(S * An2[0]),
                (_Float16)__builtin_amdgcn_exp2f(S * An2[1]),
                (_Float16)__builtin_amdgcn_exp2f(S * An2[2]),
                (_Float16)__builtin_amdgcn_exp2f(S * An2[3])};
    *(f16x4*)&hend16[cb]  = he;
    *(f16x4*)&aprod16[cb] = ap;
}

// scan pass 2: sequential carry combine (f32 in-register, fp16 storage).
__global__ __launch_bounds__(256)
void scan_carry_kernel(const _Float16* __restrict__ hend16,
                       const _Float16* __restrict__ aprod16,
                       _Float16* __restrict__ hinit16)
{
    int f = blockIdx.x * 256 + threadIdx.x;   // (dirb, d*16+n)
    int dn = f & 32767;
    int dirb = f >> 15;
    long base = (long)dirb * SCH * 32768 + dn;
    float hcur = 0.f;
#pragma unroll
    for (int c = 0; c < SCH; ++c) {
        hinit16[base + (long)c * 32768] = (_Float16)hcur;
        hcur = (float)hend16[base + (long)c * 32768]
             + (float)aprod16[base + (long)c * 32768] * hcur;
    }
}

// ---------------------------------------------------------------------------
// scan pass 3 FUSED with combine, v2: y in registers; sY/sG alias dead
// staging LDS (30KB total); stride-42 transpose buffers (2-way conflicts).
// block = (dblk, c, b): dir0 chunk c + dir1 chunk 31-c. Emits GT fp16.
// ---------------------------------------------------------------------------
__global__ __launch_bounds__(256)
void scan_p3c_kernel(const _Float16* __restrict__ u16, const _Float16* __restrict__ delta16,
                     const float* __restrict__ xdbl,
                     const float* __restrict__ Alf, const float* __restrict__ Alb,
                     const float* __restrict__ Df, const float* __restrict__ Db,
                     const _Float16* __restrict__ hinit16,
                     const _Float16* __restrict__ xz16,
                     _Float16* __restrict__ GT)
{
    __shared__ __align__(16) unsigned char smem[30720];
    _Float16* sDf = (_Float16*)(smem);            // [64][40] fp16, 5120B
    _Float16* sUf = (_Float16*)(smem + 5120);
    _Float16* sDb = (_Float16*)(smem + 10240);
    _Float16* sUb = (_Float16*)(smem + 15360);
    float*    sBf = (float*)(smem + 20480);       // [32][20] f32, 2560B
    float*    sCf = (float*)(smem + 23040);
    float*    sBb = (float*)(smem + 25600);
    float*    sCb = (float*)(smem + 28160);
    // post-recurrence aliases (staging dead after barrier): stride 42
    _Float16* sYf = (_Float16*)(smem);            // [64][42], 5376B
    _Float16* sYb = (_Float16*)(smem + 5376);
    _Float16* sG  = (_Float16*)(smem + 10752);

    const int t = threadIdx.x, wid = t >> 6, lane = t & 63;
    const int nl = lane & 3;
    const int dloc = wid * 16 + (lane >> 2);
    const int dblk = blockIdx.x, c = blockIdx.y, b = blockIdx.z;
    const int d = dblk * 64 + dloc;
    const int cB = SCH - 1 - c;
    const int T0f = c * SCL, T0b = cB * SCL;
    const int dirbF = b, dirbB = 2 + b;

    f32x4 AvF = *(const f32x4*)(Alf + d * 16 + nl * 4);
    f32x4 AvB = *(const f32x4*)(Alb + d * 16 + nl * 4);
    float AnF[4] = {-expf(AvF.x) * 1.44269504f, -expf(AvF.y) * 1.44269504f,
                    -expf(AvF.z) * 1.44269504f, -expf(AvF.w) * 1.44269504f};
    float AnB[4] = {-expf(AvB.x) * 1.44269504f, -expf(AvB.y) * 1.44269504f,
                    -expf(AvB.z) * 1.44269504f, -expf(AvB.w) * 1.44269504f};
    const float DdF = Df[d], DdB = Db[d];
    const _Float16* dpF = delta16 + ((long)dirbF * 2048 + dblk * 64) * 1024;
    const _Float16* upF = u16    + ((long)dirbF * 2048 + dblk * 64) * 1024;
    const _Float16* dpB = delta16 + ((long)dirbB * 2048 + dblk * 64) * 1024;
    const _Float16* upB = u16    + ((long)dirbB * 2048 + dblk * 64) * 1024;
    const float* BpF = xdbl + ((long)dirbF * 96 + 64) * 1024;
    const float* CpF = xdbl + ((long)dirbF * 96 + 80) * 1024;
    const float* BpB = xdbl + ((long)dirbB * 96 + 64) * 1024;
    const float* CpB = xdbl + ((long)dirbB * 96 + 80) * 1024;

    {   // stage D/U for both dirs (row stride 40 halves = 80B, 16B-aligned)
        int dd = t >> 2, q = t & 3;
        *(f16x8*)&sDf[dd * 40 + q * 8] = *(const f16x8*)&dpF[(long)dd * 1024 + T0f + q * 8];
        *(f16x8*)&sUf[dd * 40 + q * 8] = *(const f16x8*)&upF[(long)dd * 1024 + T0f + q * 8];
        *(f16x8*)&sDb[dd * 40 + q * 8] = *(const f16x8*)&dpB[(long)dd * 1024 + T0b + q * 8];
        *(f16x8*)&sUb[dd * 40 + q * 8] = *(const f16x8*)&upB[(long)dd * 1024 + T0b + q * 8];
    }
#pragma unroll
    for (int rep = 0; rep < 2; ++rep) {
        int ii = rep * 256 + t;
        int n = ii >> 5, tt = ii & 31;
        sBf[tt * 20 + n] = BpF[(long)n * 1024 + T0f + tt];
        sCf[tt * 20 + n] = CpF[(long)n * 1024 + T0f + tt];
        sBb[tt * 20 + n] = BpB[(long)n * 1024 + T0b + tt];
        sCb[tt * 20 + n] = CpB[(long)n * 1024 + T0b + tt];
    }
    long cbF = (((long)dirbF * SCH + c)  * 2048 + d) * 16 + nl * 4;
    long cbB = (((long)dirbB * SCH + cB) * 2048 + d) * 16 + nl * 4;
    f16x4 h0F = *(const f16x4*)&hinit16[cbF];
    f16x4 h0B = *(const f16x4*)&hinit16[cbB];
    const bool m[4] = {nl == 0, nl == 1, nl == 2, nl == 3};
    __syncthreads();

    float keepF[8], keepB[8];
    // dir0 recurrence -> registers
    {
        float h[4] = {(float)h0F[0], (float)h0F[1], (float)h0F[2], (float)h0F[3]};
#pragma unroll
        for (int g = 0; g < 8; ++g) {
            f16x4 dlh = *(const f16x4*)&sDf[dloc * 40 + g * 4];
            f16x4 uuh = *(const f16x4*)&sUf[dloc * 40 + g * 4];
            float dls[4] = {(float)dlh[0], (float)dlh[1], (float)dlh[2], (float)dlh[3]};
            float uus[4] = {(float)uuh[0], (float)uuh[1], (float)uuh[2], (float)uuh[3]};
            float keep = 0.f;
#pragma unroll
            for (int r4 = 0; r4 < 4; ++r4) {
                f32x4 Bv = *(const f32x4*)&sBf[(g * 4 + r4) * 20 + nl * 4];
                f32x4 Cv = *(const f32x4*)&sCf[(g * 4 + r4) * 20 + nl * 4];
                float dl = dls[r4], uu = uus[r4], t1 = dl * uu;
#pragma unroll
                for (int r = 0; r < 4; ++r)
                    h[r] = fmaf(__builtin_amdgcn_exp2f(dl * AnF[r]), h[r],
                                t1 * ((const float*)&Bv)[r]);
                float p = h[0] * Cv.x;
                p = fmaf(h[1], Cv.y, p);
                p = fmaf(h[2], Cv.z, p);
                p = fmaf(h[3], Cv.w, p);
                p = dpp_add<0xB1>(p);
                p = dpp_add<0x4E>(p);
                float fy = fmaf(DdF, uu, p);
                keep = m[r4] ? fy : keep;
            }
            keepF[g] = keep;
        }
    }
    // dir1 recurrence -> registers
    {
        float h[4] = {(float)h0B[0], (float)h0B[1], (float)h0B[2], (float)h0B[3]};
#pragma unroll
        for (int g = 0; g < 8; ++g) {
            f16x4 dlh = *(const f16x4*)&sDb[dloc * 40 + g * 4];
            f16x4 uuh = *(const f16x4*)&sUb[dloc * 40 + g * 4];
            float dls[4] = {(float)dlh[0], (float)dlh[1], (float)dlh[2], (float)dlh[3]};
            float uus[4] = {(float)uuh[0], (float)uuh[1], (float)uuh[2], (float)uuh[3]};
            float keep = 0.f;
#pragma unroll
            for (int r4 = 0; r4 < 4; ++r4) {
                f32x4 Bv = *(const f32x4*)&sBb[(g * 4 + r4) * 20 + nl * 4];
                f32x4 Cv = *(const f32x4*)&sCb[(g * 4 + r4) * 20 + nl * 4];
                float dl = dls[r4], uu = uus[r4], t1 = dl * uu;
#pragma unroll
                for (int r = 0; r < 4; ++r)
                    h[r] = fmaf(__builtin_amdgcn_exp2f(dl * AnB[r]), h[r],
                                t1 * ((const float*)&Bv)[r]);
                float p = h[0] * Cv.x;
                p = fmaf(h[1], Cv.y, p);
                p = fmaf(h[2], Cv.z, p);
                p = fmaf(h[3], Cv.w, p);
                p = dpp_add<0xB1>(p);
                p = dpp_add<0x4E>(p);
                float fy = fmaf(DdB, uu, p);
                keep = m[r4] ? fy : keep;
            }
            keepB[g] = keep;
        }
    }
    __syncthreads();   // all staging reads complete -> safe to alias

    // write y (fwd at l, bwd reversed at forward-l position), stride 42
#pragma unroll
    for (int g = 0; g < 8; ++g) {
        sYf[dloc * 42 + g * 4 + nl]        = (_Float16)keepF[g];
        sYb[dloc * 42 + 31 - (g * 4 + nl)] = (_Float16)keepB[g];
    }
    __syncthreads();

    // combine -> sG (stride 42); z read coalesced from global
    {
        int dd = t >> 2, lq = (t & 3) * 8;
        f16x8 vz = *(const f16x8*)&xz16[((long)b * 4096 + 2048 + dblk * 64 + dd) * 1024
                                        + T0f + lq];
#pragma unroll
        for (int j = 0; j < 8; ++j) {
            float z = (float)vz[j];
            float sz = z / (1.f + __builtin_amdgcn_exp2f(-z * 1.44269504f));
            float g = sz * ((float)sYf[dd * 42 + lq + j] + (float)sYb[dd * 42 + lq + j]);
            sG[dd * 42 + lq + j] = (_Float16)g;
        }
    }
    __syncthreads();

    // transpose-write GT[b][T0f+ll][dblk*64 + dq..dq+3]
#pragma unroll
    for (int rep = 0; rep < 2; ++rep) {
        int ii = rep * 256 + t;
        int ll = ii >> 4;
        int dq = (ii & 15) * 4;
        f16x4 h = {sG[dq * 42 + ll], sG[(dq + 1) * 42 + ll],
                   sG[(dq + 2) * 42 + ll], sG[(dq + 3) * 42 + ll]};
        *(f16x4*)(GT + ((long)(b * 1024 + T0f + ll)) * 2048 + dblk * 64 + dq) = h;
    }
}

extern "C" void kernel_launch(void* const* d_in, const int* in_sizes, int n_in,
                              void* d_out, int out_size, void* d_ws, size_t ws_size,
                              hipStream_t stream)
{
    const float* hidden   = (const float*)d_in[0];
    const float* inproj_w = (const float*)d_in[1];
    const float* conv_w   = (const float*)d_in[2];
    const float* conv_b   = (const float*)d_in[3];
    const float* xproj_w  = (const float*)d_in[4];
    const float* dtproj_w = (const float*)d_in[5];
    const float* dt_bias  = (const float*)d_in[6];
    const float* A_log    = (const float*)d_in[7];
    const float* D_skip   = (const float*)d_in[8];
    const float* convb_w  = (const float*)d_in[9];
    const float* convb_b  = (const float*)d_in[10];
    const float* xprojb_w = (const float*)d_in[11];
    const float* dtprojb_w= (const float*)d_in[12];
    const float* dtb_bias = (const float*)d_in[13];
    const float* Ab_log   = (const float*)d_in[14];
    const float* Db_skip  = (const float*)d_in[15];
    const float* outproj_w= (const float*)d_in[16];
    float* out = (float*)d_out;

    float* ws    = (float*)d_ws;
    float* xz    = ws;
    float* u     = ws + 8388608;
    float* xdbl  = ws + 16777216;
    float* delta = ws + 17170432;
    float* y     = ws + 25559040;
    // xz region: fp16 xz (dead after p3c) -> out_proj f32 partials
    _Float16* xz16  = (_Float16*)xz;
    float*    opart = xz;
    // u region: H16 | Win16 | u16 | Wout16; hinit16 overlays H16/Win16 later
    _Float16* H16     = (_Float16*)u;
    _Float16* Win16   = (_Float16*)(u + 1048576);
    _Float16* u16     = (_Float16*)(u + 3145728);
    _Float16* Wout16  = (_Float16*)(u + 7340032);
    _Float16* hinit16 = (_Float16*)u;
    // delta region: delta16 | xpb partials
    _Float16* delta16 = (_Float16*)delta;
    float*    xpb     = delta + 4194304;
    // y region: scratch -> hend16|aprod16 (dead after carry) -> GT
    _Float16* dw16  = (_Float16*)y;
    float*    bcat  = y + 131072;
    _Float16* xw16  = (_Float16*)(y + 135168);
    _Float16* hend16  = (_Float16*)y;
    _Float16* aprod16 = (_Float16*)(y + 2097152);
    _Float16* GT      = (_Float16*)y;              // [0, 2.1M f32) after carry

    // 0) merged setup
    hipLaunchKernelGGL(setup_kernel, dim3(4096), dim3(256), 0, stream,
        hidden, inproj_w, outproj_w, xproj_w, xprojb_w, dtproj_w, dtprojb_w,
        dt_bias, dtb_bias, H16, Win16, Wout16, xw16, dw16, bcat);

    // 1) in_proj MFMA -> fp16 xz
    hipLaunchKernelGGL((gemm_nt_f16<2, 2, 2, 4, _Float16>),
        dim3(32, 16, 2), dim3(256), 0, stream,
        H16, Win16, xz16, 1024, 1024, 1024, 1048576L, 0L, 4194304L);

    // 2) conv + silu -> u16
    hipLaunchKernelGGL(conv_silu_kernel, dim3(32768), dim3(256), 0, stream,
        xz16, conv_w, conv_b, convb_w, convb_b, u16);

    // 3) x_proj MFMA split-K + reduce
    hipLaunchKernelGGL(xproj_f16_kernel, dim3(8, XP_SK, 4), dim3(256), 0, stream,
        u16, xw16, xpb);
    hipLaunchKernelGGL(xreduce_kernel, dim3(384), dim3(256), 0, stream,
        xpb, xdbl);

    // 4) dt_proj fp16 MFMA + softplus -> delta16
    hipLaunchKernelGGL(dtproj_f16_kernel, dim3(16, 8, 4), dim3(256), 0, stream,
        xdbl, dw16, bcat, delta16);

    // 5) scan: p1 -> carry -> fused p3+combine v2 (emits GT)
    hipLaunchKernelGGL(scan_p1_kernel, dim3(32, SCH, 4), dim3(256), 0, stream,
        u16, delta16, xdbl, A_log, Ab_log, hend16, aprod16);
    hipLaunchKernelGGL(scan_carry_kernel, dim3(512), dim3(256), 0, stream,
        hend16, aprod16, hinit16);
    hipLaunchKernelGGL(scan_p3c_kernel, dim3(32, SCH, 2), dim3(256), 0, stream,
        u16, delta16, xdbl, A_log, Ab_log, D_skip, Db_skip, hinit16, xz16, GT);

    // 6) out_proj MFMA split-K=2 -> f32 partials in dead xz region
    hipLaunchKernelGGL((gemm_nt_f16<4, 1, 2, 4, float>),
        dim3(32, 8, 2), dim3(256), 0, stream,
        Wout16, GT, opart, 1024, 2048, 1024, 1024L, 1024L, 2097152L);

    // 7) out = p0 + p1
    hipLaunchKernelGGL(oreduce_kernel, dim3(2048), dim3(256), 0, stream,
        opart, out);
}